// Round 1
// baseline (1557.329 us; speedup 1.0000x reference)
//
#include <hip/hip_runtime.h>
#include <math.h>

// Problem constants
#define Bsz 4
#define Lq  1024
#define Emb 1024
#define Hh  16
#define Dd  64

// ---------------------------------------------------------------------------
// Kernel 1: fused mask bias.  bias[b,k] = kpm ? -inf : 8*log(max(mask,1e-6))
// ---------------------------------------------------------------------------
__global__ __launch_bounds__(256) void bias_kernel(const float* __restrict__ mask,
                                                   const int* __restrict__ kpm,
                                                   float* __restrict__ bias, int n)
{
    int i = blockIdx.x * 256 + threadIdx.x;
    if (i < n) {
        float b = 8.0f * logf(fmaxf(mask[i], 1e-6f));
        bias[i] = kpm[i] ? -INFINITY : b;
    }
}

// ---------------------------------------------------------------------------
// Kernel 2: C = X @ W^T + bias.   X:(4096,1024) W:(1024,1024) row-major.
// mode 0: scatter into (B,H,L,D) layout.  mode 1: plain (M,N).
// 64x64 tile, BK=16, 256 threads, 4x4 micro-tile per thread.
// ---------------------------------------------------------------------------
__global__ __launch_bounds__(256) void gemm_xwt(const float* __restrict__ X,
                                                const float* __restrict__ W,
                                                const float* __restrict__ bias,
                                                float* __restrict__ out, int mode)
{
    const int K = 1024, N = 1024;
    __shared__ float sA[16][68];
    __shared__ float sB[16][68];
    int tid = threadIdx.x;
    int bm = blockIdx.y * 64, bn = blockIdx.x * 64;
    int ty = tid >> 4, tx = tid & 15;
    int lr = tid >> 2, lk = (tid & 3) << 2;
    const float* Xp = X + (size_t)(bm + lr) * K + lk;
    const float* Wp = W + (size_t)(bn + lr) * K + lk;

    float acc[4][4];
#pragma unroll
    for (int i = 0; i < 4; ++i)
#pragma unroll
        for (int j = 0; j < 4; ++j) acc[i][j] = 0.f;

    for (int k0 = 0; k0 < K; k0 += 16) {
        float4 a4 = *(const float4*)(Xp + k0);
        float4 b4 = *(const float4*)(Wp + k0);
        __syncthreads();
        sA[lk + 0][lr] = a4.x; sA[lk + 1][lr] = a4.y;
        sA[lk + 2][lr] = a4.z; sA[lk + 3][lr] = a4.w;
        sB[lk + 0][lr] = b4.x; sB[lk + 1][lr] = b4.y;
        sB[lk + 2][lr] = b4.z; sB[lk + 3][lr] = b4.w;
        __syncthreads();
#pragma unroll
        for (int kk = 0; kk < 16; ++kk) {
            float4 av = *(const float4*)&sA[kk][ty * 4];
            float4 bv = *(const float4*)&sB[kk][tx * 4];
            float a_[4] = {av.x, av.y, av.z, av.w};
            float b_[4] = {bv.x, bv.y, bv.z, bv.w};
#pragma unroll
            for (int i = 0; i < 4; ++i)
#pragma unroll
                for (int j = 0; j < 4; ++j) acc[i][j] += a_[i] * b_[j];
        }
    }

#pragma unroll
    for (int i = 0; i < 4; ++i) {
        int m = bm + ty * 4 + i;
#pragma unroll
        for (int j = 0; j < 4; ++j) {
            int n = bn + tx * 4 + j;
            float v = acc[i][j] + bias[n];
            if (mode == 0) {
                int b = m >> 10, l = m & 1023, h = n >> 6, d = n & 63;
                out[(((size_t)(b * Hh + h)) * Lq + l) * Dd + d] = v;
            } else {
                out[(size_t)m * N + n] = v;
            }
        }
    }
}

// ---------------------------------------------------------------------------
// Kernel 3: attention.  One block per (b, 8-q-row tile), 512 threads (8 waves).
// Wave w owns q-row (q0+w).  Loops all 16 heads internally so the head-mean
// of the weights accumulates in registers (no atomics).
// ---------------------------------------------------------------------------
__global__ __launch_bounds__(512) void attn_kernel(const float* __restrict__ Qp,
                                                   const float* __restrict__ Kp,
                                                   const float* __restrict__ Vp,
                                                   const float* __restrict__ bias,
                                                   float* __restrict__ ctx,
                                                   float* __restrict__ out2)
{
    __shared__ float sS[8][1024];    // scores -> weights (wave-private rows)
    __shared__ float sKV[64][65];    // K or V chunk (64 rows x 64 d, padded)
    __shared__ float sQ[8][64];      // per-head Q tile (wave-private rows)
    __shared__ float sBias[1024];

    int tid  = threadIdx.x;
    int qt   = blockIdx.x;   // 0..127
    int b    = blockIdx.y;   // 0..3
    int q0   = qt * 8;
    int wq   = tid >> 6;     // wave id == local q row (0..7)
    int lane = tid & 63;

    sBias[tid]       = bias[b * Lq + tid];
    sBias[tid + 512] = bias[b * Lq + tid + 512];

    float o2acc[16];
#pragma unroll
    for (int j = 0; j < 16; ++j) o2acc[j] = 0.f;

    // staging index helpers: thread t loads 32B (2x float4) of a 64x64 chunk
    int srow = tid >> 3;           // 0..63
    int scol = (tid & 7) * 8;      // 0..56

    for (int h = 0; h < Hh; ++h) {
        const float* Qh = Qp + ((size_t)(b * Hh + h)) * Lq * Dd;
        const float* Kh = Kp + ((size_t)(b * Hh + h)) * Lq * Dd;
        const float* Vh = Vp + ((size_t)(b * Hh + h)) * Lq * Dd;

        sQ[wq][lane] = Qh[(q0 + wq) * Dd + lane];   // wave-private

        // ---- scores: sS[wq][k] = q . k ----
        for (int c = 0; c < 16; ++c) {
            __syncthreads();
            float4 v0 = *(const float4*)(Kh + (size_t)(c * 64 + srow) * Dd + scol);
            float4 v1 = *(const float4*)(Kh + (size_t)(c * 64 + srow) * Dd + scol + 4);
            sKV[srow][scol + 0] = v0.x; sKV[srow][scol + 1] = v0.y;
            sKV[srow][scol + 2] = v0.z; sKV[srow][scol + 3] = v0.w;
            sKV[srow][scol + 4] = v1.x; sKV[srow][scol + 5] = v1.y;
            sKV[srow][scol + 6] = v1.z; sKV[srow][scol + 7] = v1.w;
            __syncthreads();
            float acc = 0.f;
#pragma unroll
            for (int d = 0; d < 64; ++d)
                acc += sQ[wq][d] * sKV[lane][d];
            sS[wq][c * 64 + lane] = acc;
        }

        // ---- softmax over row wq (wave-private, no barrier needed) ----
        float vals[16];
        float m = -INFINITY;
#pragma unroll
        for (int j = 0; j < 16; ++j) {
            int k = lane + 64 * j;
            float v = sS[wq][k] * 0.125f + sBias[k];
            vals[j] = v;
            m = fmaxf(m, v);
        }
#pragma unroll
        for (int off = 32; off; off >>= 1)
            m = fmaxf(m, __shfl_xor(m, off, 64));
        float sum = 0.f;
#pragma unroll
        for (int j = 0; j < 16; ++j) {
            float e = expf(vals[j] - m);
            vals[j] = e;
            sum += e;
        }
#pragma unroll
        for (int off = 32; off; off >>= 1)
            sum += __shfl_xor(sum, off, 64);
        float inv = 1.0f / sum;
#pragma unroll
        for (int j = 0; j < 16; ++j) {
            float w = vals[j] * inv;
            sS[wq][lane + 64 * j] = w;
            o2acc[j] += w;                    // head-mean accumulation
        }

        // ---- PV: ctx[b, q0+wq, h*64+lane] = sum_k w[k] * V[k,lane] ----
        float oacc = 0.f;
        for (int c = 0; c < 16; ++c) {
            __syncthreads();
            float4 v0 = *(const float4*)(Vh + (size_t)(c * 64 + srow) * Dd + scol);
            float4 v1 = *(const float4*)(Vh + (size_t)(c * 64 + srow) * Dd + scol + 4);
            sKV[srow][scol + 0] = v0.x; sKV[srow][scol + 1] = v0.y;
            sKV[srow][scol + 2] = v0.z; sKV[srow][scol + 3] = v0.w;
            sKV[srow][scol + 4] = v1.x; sKV[srow][scol + 5] = v1.y;
            sKV[srow][scol + 6] = v1.z; sKV[srow][scol + 7] = v1.w;
            __syncthreads();
#pragma unroll
            for (int kr = 0; kr < 64; ++kr)
                oacc += sS[wq][c * 64 + kr] * sKV[kr][lane];
        }
        ctx[((size_t)(b * Lq + q0 + wq)) * Emb + h * Dd + lane] = oacc;
    }

    // ---- write head-mean weights ----
#pragma unroll
    for (int j = 0; j < 16; ++j)
        out2[((size_t)(b * Lq + q0 + wq)) * Lq + lane + 64 * j] = o2acc[j] * (1.0f / 16.0f);
}

// ---------------------------------------------------------------------------
extern "C" void kernel_launch(void* const* d_in, const int* in_sizes, int n_in,
                              void* d_out, int out_size, void* d_ws, size_t ws_size,
                              hipStream_t stream)
{
    const float* query = (const float*)d_in[0];
    const float* key   = (const float*)d_in[1];
    const float* value = (const float*)d_in[2];
    const float* amask = (const float*)d_in[3];
    const int*   kpm   = (const int*)d_in[4];
    const float* Wq = (const float*)d_in[5];
    const float* bq = (const float*)d_in[6];
    const float* Wk = (const float*)d_in[7];
    const float* bk = (const float*)d_in[8];
    const float* Wv = (const float*)d_in[9];
    const float* bv = (const float*)d_in[10];
    const float* Wo = (const float*)d_in[11];
    const float* bo = (const float*)d_in[12];

    float* out1 = (float*)d_out;                        // (B,L,E)
    float* out2 = out1 + (size_t)Bsz * Lq * Emb;        // (B,L,L)

    const size_t tensor_elems = (size_t)Bsz * Lq * Emb; // 4M floats
    float* Qp   = (float*)d_ws;                         // (B,H,L,D)
    float* Kp   = Qp  + tensor_elems;
    float* Vp   = Kp  + tensor_elems;
    float* ctx  = Vp  + tensor_elems;                   // (B,L,E)
    float* bias = ctx + tensor_elems;                   // (B,L)

    bias_kernel<<<16, 256, 0, stream>>>(amask, kpm, bias, Bsz * Lq);

    dim3 gg(16, 64), gb(256);
    gemm_xwt<<<gg, gb, 0, stream>>>(query, Wq, bq, Qp, 0);
    gemm_xwt<<<gg, gb, 0, stream>>>(key,   Wk, bk, Kp, 0);
    gemm_xwt<<<gg, gb, 0, stream>>>(value, Wv, bv, Vp, 0);

    attn_kernel<<<dim3(128, 4), 512, 0, stream>>>(Qp, Kp, Vp, bias, ctx, out2);

    gemm_xwt<<<gg, gb, 0, stream>>>(ctx, Wo, bo, out1, 1);
}

// Round 2
// 409.327 us; speedup vs baseline: 3.8046x; 3.8046x over previous
//
#include <hip/hip_runtime.h>
#include <math.h>

#define Bsz 4
#define Lq  1024
#define Emb 1024
#define Hh  16
#define Dd  64

typedef short bf16x8 __attribute__((ext_vector_type(8)));
typedef float f32x4 __attribute__((ext_vector_type(4)));

static __device__ __forceinline__ unsigned short f2bf(float f) {
    unsigned u = __float_as_uint(f);
    return (unsigned short)((u + 0x7FFFu + ((u >> 16) & 1u)) >> 16);
}
// pack two f32 -> two bf16 (round-half-up) in one v_perm
static __device__ __forceinline__ unsigned pack2(float lo, float hi) {
    return __builtin_amdgcn_perm(__float_as_uint(hi) + 0x8000u,
                                 __float_as_uint(lo) + 0x8000u, 0x07060302u);
}

// ---------------------------------------------------------------------------
__global__ __launch_bounds__(256) void bias_kernel(const float* __restrict__ mask,
                                                   const int* __restrict__ kpm,
                                                   float* __restrict__ bias, int n)
{
    int i = blockIdx.x * 256 + threadIdx.x;
    if (i < n) {
        float b = 8.0f * logf(fmaxf(mask[i], 1e-6f));
        bias[i] = kpm[i] ? -INFINITY : b;
    }
}

// ---------------------------------------------------------------------------
__global__ __launch_bounds__(256) void cvt_bf16(const float* __restrict__ in,
                                                unsigned short* __restrict__ out, int n4)
{
    int i = blockIdx.x * 256 + threadIdx.x;
    if (i < n4) {
        float4 v = ((const float4*)in)[i];
        ushort4 o;
        o.x = f2bf(v.x); o.y = f2bf(v.y); o.z = f2bf(v.z); o.w = f2bf(v.w);
        ((ushort4*)out)[i] = o;
    }
}

// ---------------------------------------------------------------------------
// C = A(M,K) @ B(N,K)^T + bias.  bf16 in, fp32 accum.  128x128 tile, BK=32,
// 256 thr / 4 waves, each wave a 64x64 subtile = 4x4 MFMA 16x16x32 frags.
// MODE 0: bf16 out scattered to (B,H,L,D). MODE 1: f32 out (M,N).
// MODE 2: bf16 out scattered to (B,H,D,L)  (transposed V for PV frags).
// ---------------------------------------------------------------------------
template<int MODE>
__global__ __launch_bounds__(256) void gemm_bf16(const unsigned short* __restrict__ A,
                                                 const unsigned short* __restrict__ Bw,
                                                 const float* __restrict__ bias,
                                                 void* __restrict__ outp)
{
    const int K = 1024;
    __shared__ unsigned short sA[128][40];   // +8 pad: ~2-way banks on b128 frag reads
    __shared__ unsigned short sB[128][40];
    int tid = threadIdx.x;
    int bm = blockIdx.y * 128, bn = blockIdx.x * 128;
    int w = tid >> 6, lane = tid & 63;
    int wr = (w >> 1) * 64, wc = (w & 1) * 64;
    int fr = lane & 15, fk = (lane >> 4) * 8;
    int srow = tid >> 1, skc = (tid & 1) * 16;
    const unsigned short* Ap = A + (size_t)(bm + srow) * K + skc;
    const unsigned short* Bp = Bw + (size_t)(bn + srow) * K + skc;

    f32x4 acc[4][4];
#pragma unroll
    for (int i = 0; i < 4; ++i)
#pragma unroll
        for (int j = 0; j < 4; ++j) acc[i][j] = (f32x4){0.f, 0.f, 0.f, 0.f};

    for (int k0 = 0; k0 < K; k0 += 32) {
        bf16x8 a0 = *(const bf16x8*)(Ap + k0);
        bf16x8 a1 = *(const bf16x8*)(Ap + k0 + 8);
        bf16x8 b0 = *(const bf16x8*)(Bp + k0);
        bf16x8 b1 = *(const bf16x8*)(Bp + k0 + 8);
        __syncthreads();
        *(bf16x8*)&sA[srow][skc]     = a0;
        *(bf16x8*)&sA[srow][skc + 8] = a1;
        *(bf16x8*)&sB[srow][skc]     = b0;
        *(bf16x8*)&sB[srow][skc + 8] = b1;
        __syncthreads();
        bf16x8 af[4], bfv[4];
#pragma unroll
        for (int i = 0; i < 4; ++i) af[i]  = *(const bf16x8*)&sA[wr + i * 16 + fr][fk];
#pragma unroll
        for (int j = 0; j < 4; ++j) bfv[j] = *(const bf16x8*)&sB[wc + j * 16 + fr][fk];
#pragma unroll
        for (int i = 0; i < 4; ++i)
#pragma unroll
            for (int j = 0; j < 4; ++j)
                acc[i][j] = __builtin_amdgcn_mfma_f32_16x16x32_bf16(af[i], bfv[j], acc[i][j], 0, 0, 0);
    }

    int rb = (lane >> 4) * 4;
#pragma unroll
    for (int j = 0; j < 4; ++j) {
        int n = bn + wc + j * 16 + fr;
        float bia = bias[n];
#pragma unroll
        for (int i = 0; i < 4; ++i) {
#pragma unroll
            for (int r = 0; r < 4; ++r) {
                int m = bm + wr + i * 16 + rb + r;
                float v = acc[i][j][r] + bia;
                if (MODE == 0) {
                    int b = m >> 10, l = m & 1023, h = n >> 6, d = n & 63;
                    ((unsigned short*)outp)[(((size_t)(b * Hh + h)) * Lq + l) * Dd + d] = f2bf(v);
                } else if (MODE == 1) {
                    ((float*)outp)[(size_t)m * 1024 + n] = v;
                } else {
                    int b = m >> 10, l = m & 1023, h = n >> 6, d = n & 63;
                    ((unsigned short*)outp)[(((size_t)(b * Hh + h)) * Dd + d) * Lq + l] = f2bf(v);
                }
            }
        }
    }
}

// ---------------------------------------------------------------------------
// Attention.  Block = (qtile of 16 rows, b, head-group of 8).  256 thr/4 waves.
// Scores tile S[16][1024] f32 in dynamic LDS, XOR-swizzled: k ^= (q&7)<<2.
// QK^T/PV operand frags load straight from global (K/V L2-resident per b).
// Head-mean weights accumulate in registers; hg0 -> out2, hg1 -> part.
// ---------------------------------------------------------------------------
#define SWZ(q, k) ((k) ^ (((q) & 7) << 2))

__global__ __launch_bounds__(256) void attn_mfma(const unsigned short* __restrict__ Qh,
                                                 const unsigned short* __restrict__ Kh,
                                                 const unsigned short* __restrict__ Vt,
                                                 const float* __restrict__ mbias,
                                                 unsigned short* __restrict__ ctx,
                                                 float* __restrict__ o2a,
                                                 float* __restrict__ o2b)
{
    extern __shared__ char smem[];
    float* S = (float*)smem;                       // [16][1024] swizzled
    float* sBias = (float*)(smem + 16 * 1024 * 4); // [1024]

    int tid = threadIdx.x;
    int w = tid >> 6, lane = tid & 63;
    int qt = blockIdx.x, b = blockIdx.y, hg = blockIdx.z;
    int q0 = qt * 16;
    int fr = lane & 15, fg = lane >> 4, fk = fg * 8;

    for (int i = tid; i < 1024; i += 256) sBias[i] = mbias[b * Lq + i];

    float o2[4][16];
#pragma unroll
    for (int rr = 0; rr < 4; ++rr)
#pragma unroll
        for (int j = 0; j < 16; ++j) o2[rr][j] = 0.f;

    for (int hi = 0; hi < 8; ++hi) {
        int h = hg * 8 + hi;
        const unsigned short* Qp = Qh + ((size_t)(b * Hh + h)) * Lq * Dd;
        const unsigned short* Kp = Kh + ((size_t)(b * Hh + h)) * Lq * Dd;
        const unsigned short* Vp = Vt + ((size_t)(b * Hh + h)) * Dd * Lq;

        bf16x8 aq0 = *(const bf16x8*)(Qp + (size_t)(q0 + fr) * Dd + fk);
        bf16x8 aq1 = *(const bf16x8*)(Qp + (size_t)(q0 + fr) * Dd + fk + 32);

        __syncthreads();   // previous head's PV reads of S are done

        // ---- QK^T: wave w covers kcols c*64 + w*16 + fr ----
#pragma unroll 4
        for (int c = 0; c < 16; ++c) {
            int kc = c * 64 + w * 16 + fr;
            bf16x8 bk0 = *(const bf16x8*)(Kp + (size_t)kc * Dd + fk);
            bf16x8 bk1 = *(const bf16x8*)(Kp + (size_t)kc * Dd + fk + 32);
            f32x4 s = (f32x4){0.f, 0.f, 0.f, 0.f};
            s = __builtin_amdgcn_mfma_f32_16x16x32_bf16(aq0, bk0, s, 0, 0, 0);
            s = __builtin_amdgcn_mfma_f32_16x16x32_bf16(aq1, bk1, s, 0, 0, 0);
#pragma unroll
            for (int r = 0; r < 4; ++r) {
                int q = fg * 4 + r;
                S[q * 1024 + SWZ(q, kc)] = s[r] * 0.125f;
            }
        }
        __syncthreads();

        // ---- softmax: wave w owns rows w*4 .. w*4+3 ----
#pragma unroll
        for (int rr = 0; rr < 4; ++rr) {
            int q = w * 4 + rr;
            float vals[16];
            float mx = -INFINITY;
#pragma unroll
            for (int j = 0; j < 16; ++j) {
                int k = lane + 64 * j;
                float v = S[q * 1024 + SWZ(q, k)] + sBias[k];
                vals[j] = v; mx = fmaxf(mx, v);
            }
#pragma unroll
            for (int off = 32; off; off >>= 1) mx = fmaxf(mx, __shfl_xor(mx, off, 64));
            float sum = 0.f;
#pragma unroll
            for (int j = 0; j < 16; ++j) { float e = __expf(vals[j] - mx); vals[j] = e; sum += e; }
#pragma unroll
            for (int off = 32; off; off >>= 1) sum += __shfl_xor(sum, off, 64);
            float inv = 1.f / sum;
#pragma unroll
            for (int j = 0; j < 16; ++j) {
                float p = vals[j] * inv;
                int k = lane + 64 * j;
                S[q * 1024 + SWZ(q, k)] = p;
                o2[rr][j] += p;
            }
        }
        __syncthreads();

        // ---- PV: wave w owns d-cols w*16 .. w*16+15 ----
        f32x4 oa = (f32x4){0.f, 0.f, 0.f, 0.f};
#pragma unroll 4
        for (int c = 0; c < 16; ++c) {
            int k0 = c * 64;
            float4 p0 = *(const float4*)&S[fr * 1024 + SWZ(fr, k0 + fk)];
            float4 p1 = *(const float4*)&S[fr * 1024 + SWZ(fr, k0 + fk + 4)];
            float4 p2 = *(const float4*)&S[fr * 1024 + SWZ(fr, k0 + 32 + fk)];
            float4 p3 = *(const float4*)&S[fr * 1024 + SWZ(fr, k0 + 32 + fk + 4)];
            union { bf16x8 v; unsigned u[4]; } pa0, pa1;
            pa0.u[0] = pack2(p0.x, p0.y); pa0.u[1] = pack2(p0.z, p0.w);
            pa0.u[2] = pack2(p1.x, p1.y); pa0.u[3] = pack2(p1.z, p1.w);
            pa1.u[0] = pack2(p2.x, p2.y); pa1.u[1] = pack2(p2.z, p2.w);
            pa1.u[2] = pack2(p3.x, p3.y); pa1.u[3] = pack2(p3.z, p3.w);
            bf16x8 bv0 = *(const bf16x8*)(Vp + (size_t)(w * 16 + fr) * Lq + k0 + fk);
            bf16x8 bv1 = *(const bf16x8*)(Vp + (size_t)(w * 16 + fr) * Lq + k0 + 32 + fk);
            oa = __builtin_amdgcn_mfma_f32_16x16x32_bf16(pa0.v, bv0, oa, 0, 0, 0);
            oa = __builtin_amdgcn_mfma_f32_16x16x32_bf16(pa1.v, bv1, oa, 0, 0, 0);
        }
#pragma unroll
        for (int r = 0; r < 4; ++r) {
            int q = fg * 4 + r;
            ctx[((size_t)(b * Lq + q0 + q)) * Emb + h * Dd + w * 16 + fr] = f2bf(oa[r]);
        }
    }

    float* dst = (hg == 0) ? o2a : o2b;   // raw sums over 8 heads
#pragma unroll
    for (int rr = 0; rr < 4; ++rr) {
        int q = w * 4 + rr;
#pragma unroll
        for (int j = 0; j < 16; ++j)
            dst[((size_t)(b * Lq + q0 + q)) * Lq + lane + 64 * j] = o2[rr][j];
    }
}

// ---------------------------------------------------------------------------
__global__ __launch_bounds__(256) void combine_o2(float* __restrict__ o2,
                                                  const float* __restrict__ part, int n4)
{
    int i = blockIdx.x * 256 + threadIdx.x;
    if (i < n4) {
        float4 a = ((float4*)o2)[i];
        float4 p = ((const float4*)part)[i];
        a.x = (a.x + p.x) * 0.0625f; a.y = (a.y + p.y) * 0.0625f;
        a.z = (a.z + p.z) * 0.0625f; a.w = (a.w + p.w) * 0.0625f;
        ((float4*)o2)[i] = a;
    }
}

// ---------------------------------------------------------------------------
extern "C" void kernel_launch(void* const* d_in, const int* in_sizes, int n_in,
                              void* d_out, int out_size, void* d_ws, size_t ws_size,
                              hipStream_t stream)
{
    const float* query = (const float*)d_in[0];
    const float* key   = (const float*)d_in[1];
    const float* value = (const float*)d_in[2];
    const float* amask = (const float*)d_in[3];
    const int*   kpm   = (const int*)d_in[4];
    const float* Wq = (const float*)d_in[5];
    const float* bq = (const float*)d_in[6];
    const float* Wk = (const float*)d_in[7];
    const float* bk = (const float*)d_in[8];
    const float* Wv = (const float*)d_in[9];
    const float* bv = (const float*)d_in[10];
    const float* Wo = (const float*)d_in[11];
    const float* bo = (const float*)d_in[12];

    float* out1 = (float*)d_out;                       // (B,L,E) f32
    float* out2 = out1 + (size_t)Bsz * Lq * Emb;       // (B,L,L) f32

    const size_t MB = 1u << 20;
    char* ws = (char*)d_ws;
    unsigned short* qbf = (unsigned short*)(ws + 0 * MB);   // 8 MB
    unsigned short* kbf = (unsigned short*)(ws + 8 * MB);   // 8 MB
    unsigned short* vbf = (unsigned short*)(ws + 16 * MB);  // 8 MB
    unsigned short* wqb = (unsigned short*)(ws + 24 * MB);  // 2 MB
    unsigned short* wkb = (unsigned short*)(ws + 26 * MB);
    unsigned short* wvb = (unsigned short*)(ws + 28 * MB);
    unsigned short* wob = (unsigned short*)(ws + 30 * MB);
    unsigned short* QhB = (unsigned short*)(ws + 32 * MB);  // (B,H,L,D) bf16
    unsigned short* KhB = (unsigned short*)(ws + 40 * MB);
    unsigned short* VtB = (unsigned short*)(ws + 48 * MB);  // (B,H,D,L) bf16
    unsigned short* ctxB = (unsigned short*)(ws + 56 * MB); // (B,L,E) bf16
    float* mbias = (float*)(ws + 64 * MB);                  // 16 KB
    float* part  = (float*)(ws + 0 * MB);  // 16 MB f32, aliases qbf/kbf (dead by attn)

    bias_kernel<<<16, 256, 0, stream>>>(amask, kpm, mbias, Bsz * Lq);

    cvt_bf16<<<4096, 256, 0, stream>>>(query, qbf, 1048576);
    cvt_bf16<<<4096, 256, 0, stream>>>(key,   kbf, 1048576);
    cvt_bf16<<<4096, 256, 0, stream>>>(value, vbf, 1048576);
    cvt_bf16<<<1024, 256, 0, stream>>>(Wq, wqb, 262144);
    cvt_bf16<<<1024, 256, 0, stream>>>(Wk, wkb, 262144);
    cvt_bf16<<<1024, 256, 0, stream>>>(Wv, wvb, 262144);
    cvt_bf16<<<1024, 256, 0, stream>>>(Wo, wob, 262144);

    dim3 gg(8, 32), gb(256);
    gemm_bf16<0><<<gg, gb, 0, stream>>>(qbf, wqb, bq, QhB);
    gemm_bf16<0><<<gg, gb, 0, stream>>>(kbf, wkb, bk, KhB);
    gemm_bf16<2><<<gg, gb, 0, stream>>>(vbf, wvb, bv, VtB);

    attn_mfma<<<dim3(64, 4, 2), 256, 69632, stream>>>(QhB, KhB, VtB, mbias, ctxB, out2, part);

    combine_o2<<<4096, 256, 0, stream>>>(out2, part, 1048576);

    gemm_bf16<1><<<gg, gb, 0, stream>>>(ctxB, wob, bo, out1);
}

// Round 3
// 319.919 us; speedup vs baseline: 4.8679x; 1.2795x over previous
//
#include <hip/hip_runtime.h>
#include <math.h>

#define Bsz 4
#define Lq  1024
#define Emb 1024
#define Hh  16
#define Dd  64

typedef short bf16x8 __attribute__((ext_vector_type(8)));
typedef float f32x4 __attribute__((ext_vector_type(4)));

static __device__ __forceinline__ unsigned short f2bf(float f) {
    unsigned u = __float_as_uint(f);
    return (unsigned short)((u + 0x7FFFu + ((u >> 16) & 1u)) >> 16);
}
// pack two f32 -> two bf16 (round-half-up) in one v_perm
static __device__ __forceinline__ unsigned pack2(float lo, float hi) {
    return __builtin_amdgcn_perm(__float_as_uint(hi) + 0x8000u,
                                 __float_as_uint(lo) + 0x8000u, 0x07060302u);
}

// ---------------------------------------------------------------------------
__global__ __launch_bounds__(256) void bias_kernel(const float* __restrict__ mask,
                                                   const int* __restrict__ kpm,
                                                   float* __restrict__ bias, int n)
{
    int i = blockIdx.x * 256 + threadIdx.x;
    if (i < n) {
        float b = 8.0f * logf(fmaxf(mask[i], 1e-6f));
        bias[i] = kpm[i] ? -INFINITY : b;
    }
}

// ---------------------------------------------------------------------------
__global__ __launch_bounds__(256) void cvt_bf16(const float* __restrict__ in,
                                                unsigned short* __restrict__ out, int n4)
{
    int i = blockIdx.x * 256 + threadIdx.x;
    if (i < n4) {
        float4 v = ((const float4*)in)[i];
        ushort4 o;
        o.x = f2bf(v.x); o.y = f2bf(v.y); o.z = f2bf(v.z); o.w = f2bf(v.w);
        ((ushort4*)out)[i] = o;
    }
}

// ---------------------------------------------------------------------------
// C = A(M,K) @ B(N,K)^T + bias.  bf16 in, fp32 accum.  128x128 tile, BK=32.
// MODE 0: bf16 out scattered to (B,H,L,D). MODE 1: f32 out (M,N).
// MODE 2: bf16 out scattered to (B,H,D,L)  (transposed V for PV frags).
// ---------------------------------------------------------------------------
template<int MODE>
__global__ __launch_bounds__(256) void gemm_bf16(const unsigned short* __restrict__ A,
                                                 const unsigned short* __restrict__ Bw,
                                                 const float* __restrict__ bias,
                                                 void* __restrict__ outp)
{
    const int K = 1024;
    __shared__ unsigned short sA[128][40];
    __shared__ unsigned short sB[128][40];
    int tid = threadIdx.x;
    int bm = blockIdx.y * 128, bn = blockIdx.x * 128;
    int w = tid >> 6, lane = tid & 63;
    int wr = (w >> 1) * 64, wc = (w & 1) * 64;
    int fr = lane & 15, fk = (lane >> 4) * 8;
    int srow = tid >> 1, skc = (tid & 1) * 16;
    const unsigned short* Ap = A + (size_t)(bm + srow) * K + skc;
    const unsigned short* Bp = Bw + (size_t)(bn + srow) * K + skc;

    f32x4 acc[4][4];
#pragma unroll
    for (int i = 0; i < 4; ++i)
#pragma unroll
        for (int j = 0; j < 4; ++j) acc[i][j] = (f32x4){0.f, 0.f, 0.f, 0.f};

    for (int k0 = 0; k0 < K; k0 += 32) {
        bf16x8 a0 = *(const bf16x8*)(Ap + k0);
        bf16x8 a1 = *(const bf16x8*)(Ap + k0 + 8);
        bf16x8 b0 = *(const bf16x8*)(Bp + k0);
        bf16x8 b1 = *(const bf16x8*)(Bp + k0 + 8);
        __syncthreads();
        *(bf16x8*)&sA[srow][skc]     = a0;
        *(bf16x8*)&sA[srow][skc + 8] = a1;
        *(bf16x8*)&sB[srow][skc]     = b0;
        *(bf16x8*)&sB[srow][skc + 8] = b1;
        __syncthreads();
        bf16x8 af[4], bfv[4];
#pragma unroll
        for (int i = 0; i < 4; ++i) af[i]  = *(const bf16x8*)&sA[wr + i * 16 + fr][fk];
#pragma unroll
        for (int j = 0; j < 4; ++j) bfv[j] = *(const bf16x8*)&sB[wc + j * 16 + fr][fk];
#pragma unroll
        for (int i = 0; i < 4; ++i)
#pragma unroll
            for (int j = 0; j < 4; ++j)
                acc[i][j] = __builtin_amdgcn_mfma_f32_16x16x32_bf16(af[i], bfv[j], acc[i][j], 0, 0, 0);
    }

    int rb = (lane >> 4) * 4;
#pragma unroll
    for (int j = 0; j < 4; ++j) {
        int n = bn + wc + j * 16 + fr;
        float bia = bias[n];
#pragma unroll
        for (int i = 0; i < 4; ++i) {
#pragma unroll
            for (int r = 0; r < 4; ++r) {
                int m = bm + wr + i * 16 + rb + r;
                float v = acc[i][j][r] + bia;
                if (MODE == 0) {
                    int b = m >> 10, l = m & 1023, h = n >> 6, d = n & 63;
                    ((unsigned short*)outp)[(((size_t)(b * Hh + h)) * Lq + l) * Dd + d] = f2bf(v);
                } else if (MODE == 1) {
                    ((float*)outp)[(size_t)m * 1024 + n] = v;
                } else {
                    int b = m >> 10, l = m & 1023, h = n >> 6, d = n & 63;
                    ((unsigned short*)outp)[(((size_t)(b * Hh + h)) * Dd + d) * Lq + l] = f2bf(v);
                }
            }
        }
    }
}

// ---------------------------------------------------------------------------
// Pass C: flash attention.  Block = (qt64, b, h), 256 thr / 4 waves, each wave
// owns 16 q-rows.  Swapped QK^T (mfma(K,Q)) -> lane holds 16 k-vals of one
// q-row (q = q0w + lane&15): in-lane max/sum + shfl_xor(16,32).  P goes
// through a wave-private XOR-swizzled LDS tile to become the PV A-fragment.
// Emits ctx (bf16) and per-row stats m, 1/l for the out2 pass.
// ---------------------------------------------------------------------------
__global__ __launch_bounds__(256) void attn_flash(const unsigned short* __restrict__ Qh,
                                                  const unsigned short* __restrict__ Kh,
                                                  const unsigned short* __restrict__ Vt,
                                                  const float* __restrict__ mbias,
                                                  unsigned short* __restrict__ ctx,
                                                  float* __restrict__ mstats,
                                                  float* __restrict__ lstats)
{
    __shared__ float sBias[1024];
    __shared__ unsigned short Wl[4][16][64];   // per-wave P tile, XOR-swizzled

    int tid = threadIdx.x;
    int w = tid >> 6, lane = tid & 63;
    int fr = lane & 15, fg = lane >> 4;
    int qt = blockIdx.x, b = blockIdx.y, h = blockIdx.z;
    int q0w = qt * 64 + w * 16;
    int swz = (fr & 7) << 2;                   // XOR on 4-byte-word index

    for (int i = tid; i < 1024; i += 256) sBias[i] = mbias[b * Lq + i];
    __syncthreads();

    const unsigned short* Qp = Qh + ((size_t)(b * Hh + h)) * Lq * Dd;
    const unsigned short* Kp = Kh + ((size_t)(b * Hh + h)) * Lq * Dd;
    const unsigned short* Vp = Vt + ((size_t)(b * Hh + h)) * Dd * Lq;

    bf16x8 bq0 = *(const bf16x8*)(Qp + (size_t)(q0w + fr) * Dd + fg * 8);
    bf16x8 bq1 = *(const bf16x8*)(Qp + (size_t)(q0w + fr) * Dd + 32 + fg * 8);

    f32x4 O[4];
#pragma unroll
    for (int dt = 0; dt < 4; ++dt) O[dt] = (f32x4){0.f, 0.f, 0.f, 0.f};
    float m_run = -INFINITY, l_run = 0.f;

    for (int c = 0; c < 16; ++c) {
        int kc = c * 64;
        // ---- swapped QK^T: s[kt][r] <-> (k = kc+kt*16+fg*4+r, q = q0w+fr) ----
        f32x4 s[4];
        bf16x8 a0[4], a1[4];
#pragma unroll
        for (int kt = 0; kt < 4; ++kt) a0[kt] = *(const bf16x8*)(Kp + (size_t)(kc + kt * 16 + fr) * Dd + fg * 8);
#pragma unroll
        for (int kt = 0; kt < 4; ++kt) a1[kt] = *(const bf16x8*)(Kp + (size_t)(kc + kt * 16 + fr) * Dd + 32 + fg * 8);
#pragma unroll
        for (int kt = 0; kt < 4; ++kt) {
            s[kt] = __builtin_amdgcn_mfma_f32_16x16x32_bf16(a0[kt], bq0, (f32x4){0.f, 0.f, 0.f, 0.f}, 0, 0, 0);
            s[kt] = __builtin_amdgcn_mfma_f32_16x16x32_bf16(a1[kt], bq1, s[kt], 0, 0, 0);
        }
        // ---- bias + max (in-lane 16 + cross-fg shfl) ----
        float v_[16];
        float pmax = -INFINITY;
#pragma unroll
        for (int kt = 0; kt < 4; ++kt) {
            float4 bb = *(const float4*)&sBias[kc + kt * 16 + fg * 4];
#pragma unroll
            for (int r = 0; r < 4; ++r) {
                float v = s[kt][r] * 0.125f + (&bb.x)[r];
                v_[kt * 4 + r] = v;
                pmax = fmaxf(pmax, v);
            }
        }
        pmax = fmaxf(pmax, __shfl_xor(pmax, 16, 64));
        pmax = fmaxf(pmax, __shfl_xor(pmax, 32, 64));
        float m_new = fmaxf(m_run, pmax);
        float scale = __expf(m_run - m_new);     // 0 on first chunk
        float csum = 0.f;
#pragma unroll
        for (int i = 0; i < 16; ++i) { float e = __expf(v_[i] - m_new); v_[i] = e; csum += e; }
        csum += __shfl_xor(csum, 16, 64);
        csum += __shfl_xor(csum, 32, 64);
        l_run = l_run * scale + csum;
        m_run = m_new;
        // ---- rescale O (O rows are q = fg*4+r; scale lives at lane q) ----
#pragma unroll
        for (int r = 0; r < 4; ++r) {
            float sr = __shfl(scale, fg * 4 + r, 64);
#pragma unroll
            for (int dt = 0; dt < 4; ++dt) O[dt][r] *= sr;
        }
        // ---- pack P -> swizzled wave-private LDS ----
#pragma unroll
        for (int kt = 0; kt < 4; ++kt) {
            unsigned w0 = pack2(v_[kt * 4 + 0], v_[kt * 4 + 1]);
            unsigned w1 = pack2(v_[kt * 4 + 2], v_[kt * 4 + 3]);
            int base = kt * 8 + fg * 2;          // 4-byte-word index of k-pair
            uint2 pr; pr.x = w0; pr.y = w1;
            *(uint2*)&Wl[w][fr][2 * (base ^ swz)] = pr;
        }
        bf16x8 pa0 = *(const bf16x8*)&Wl[w][fr][2 * ((fg * 4) ^ swz)];
        bf16x8 pa1 = *(const bf16x8*)&Wl[w][fr][2 * ((16 + fg * 4) ^ swz)];
        // ---- PV: O[dt] += P(16q x 64k) @ V(64k x 16d) ----
#pragma unroll
        for (int dt = 0; dt < 4; ++dt) {
            bf16x8 vb0 = *(const bf16x8*)(Vp + (size_t)(dt * 16 + fr) * Lq + kc + fg * 8);
            bf16x8 vb1 = *(const bf16x8*)(Vp + (size_t)(dt * 16 + fr) * Lq + kc + 32 + fg * 8);
            O[dt] = __builtin_amdgcn_mfma_f32_16x16x32_bf16(pa0, vb0, O[dt], 0, 0, 0);
            O[dt] = __builtin_amdgcn_mfma_f32_16x16x32_bf16(pa1, vb1, O[dt], 0, 0, 0);
        }
    }

    float linv = 1.f / l_run;
#pragma unroll
    for (int r = 0; r < 4; ++r) {
        float lr = __shfl(linv, fg * 4 + r, 64);
#pragma unroll
        for (int dt = 0; dt < 4; ++dt) O[dt][r] *= lr;
    }
#pragma unroll
    for (int dt = 0; dt < 4; ++dt)
#pragma unroll
        for (int r = 0; r < 4; ++r)
            ctx[((size_t)(b * Lq + q0w + fg * 4 + r)) * Emb + h * Dd + dt * 16 + fr] = f2bf(O[dt][r]);

    if (lane < 16) {
        mstats[(size_t)(b * Hh + h) * Lq + q0w + lane] = m_run;
        lstats[(size_t)(b * Hh + h) * Lq + q0w + lane] = linv;
    }
}

// ---------------------------------------------------------------------------
// Pass B: out2 = mean_h softmax weights.  Block = (qt32, kc128, b), 256 thr.
// Recomputes QK^T per head and applies exp(s+bias-m)*linv straight from MFMA
// output registers (stats from pass C) -- no reductions, no main-loop barriers.
// ---------------------------------------------------------------------------
__global__ __launch_bounds__(256) void attn_out2(const unsigned short* __restrict__ Qh,
                                                 const unsigned short* __restrict__ Kh,
                                                 const float* __restrict__ mbias,
                                                 const float* __restrict__ mstats,
                                                 const float* __restrict__ lstats,
                                                 float* __restrict__ out2)
{
    __shared__ float sM[16][32];
    __shared__ float sLi[16][32];
    int tid = threadIdx.x;
    int w = tid >> 6, lane = tid & 63;
    int fr = lane & 15, fg = lane >> 4;
    int q0 = blockIdx.x * 32;
    int kc = blockIdx.y * 128;
    int b  = blockIdx.z;

    for (int i = tid; i < 512; i += 256) {
        int h = i >> 5, qq = i & 31;
        sM[h][qq]  = mstats[(size_t)(b * Hh + h) * Lq + q0 + qq];
        sLi[h][qq] = lstats[(size_t)(b * Hh + h) * Lq + q0 + qq];
    }
    __syncthreads();

    float bias0 = mbias[b * Lq + kc + w * 32 + fr];
    float bias1 = mbias[b * Lq + kc + w * 32 + 16 + fr];

    float o2[2][2][4];
#pragma unroll
    for (int rt = 0; rt < 2; ++rt)
#pragma unroll
        for (int ct = 0; ct < 2; ++ct)
#pragma unroll
            for (int r = 0; r < 4; ++r) o2[rt][ct][r] = 0.f;

    for (int h = 0; h < Hh; ++h) {
        const unsigned short* Qp = Qh + ((size_t)(b * Hh + h)) * Lq * Dd;
        const unsigned short* Kp = Kh + ((size_t)(b * Hh + h)) * Lq * Dd;
        bf16x8 aq[2][2], bk[2][2];
#pragma unroll
        for (int rt = 0; rt < 2; ++rt)
#pragma unroll
            for (int ks = 0; ks < 2; ++ks)
                aq[rt][ks] = *(const bf16x8*)(Qp + (size_t)(q0 + rt * 16 + fr) * Dd + ks * 32 + fg * 8);
#pragma unroll
        for (int ct = 0; ct < 2; ++ct)
#pragma unroll
            for (int ks = 0; ks < 2; ++ks)
                bk[ct][ks] = *(const bf16x8*)(Kp + (size_t)(kc + w * 32 + ct * 16 + fr) * Dd + ks * 32 + fg * 8);
        float4 mrow[2], lirow[2];
#pragma unroll
        for (int rt = 0; rt < 2; ++rt) {
            mrow[rt]  = *(const float4*)&sM[h][rt * 16 + fg * 4];
            lirow[rt] = *(const float4*)&sLi[h][rt * 16 + fg * 4];
        }
#pragma unroll
        for (int rt = 0; rt < 2; ++rt)
#pragma unroll
            for (int ct = 0; ct < 2; ++ct) {
                f32x4 s = __builtin_amdgcn_mfma_f32_16x16x32_bf16(aq[rt][0], bk[ct][0], (f32x4){0.f, 0.f, 0.f, 0.f}, 0, 0, 0);
                s = __builtin_amdgcn_mfma_f32_16x16x32_bf16(aq[rt][1], bk[ct][1], s, 0, 0, 0);
                float bia = ct ? bias1 : bias0;
#pragma unroll
                for (int r = 0; r < 4; ++r)
                    o2[rt][ct][r] += __expf(s[r] * 0.125f + bia - mrow[rt][r]) * lirow[rt][r];
            }
    }

#pragma unroll
    for (int rt = 0; rt < 2; ++rt)
#pragma unroll
        for (int ct = 0; ct < 2; ++ct)
#pragma unroll
            for (int r = 0; r < 4; ++r)
                out2[((size_t)(b * Lq + q0 + rt * 16 + fg * 4 + r)) * Lq + kc + w * 32 + ct * 16 + fr]
                    = o2[rt][ct][r] * 0.0625f;
}

// ---------------------------------------------------------------------------
extern "C" void kernel_launch(void* const* d_in, const int* in_sizes, int n_in,
                              void* d_out, int out_size, void* d_ws, size_t ws_size,
                              hipStream_t stream)
{
    const float* query = (const float*)d_in[0];
    const float* key   = (const float*)d_in[1];
    const float* value = (const float*)d_in[2];
    const float* amask = (const float*)d_in[3];
    const int*   kpm   = (const int*)d_in[4];
    const float* Wq = (const float*)d_in[5];
    const float* bq = (const float*)d_in[6];
    const float* Wk = (const float*)d_in[7];
    const float* bk = (const float*)d_in[8];
    const float* Wv = (const float*)d_in[9];
    const float* bv = (const float*)d_in[10];
    const float* Wo = (const float*)d_in[11];
    const float* bo = (const float*)d_in[12];

    float* out1 = (float*)d_out;                       // (B,L,E) f32
    float* out2 = out1 + (size_t)Bsz * Lq * Emb;       // (B,L,L) f32

    const size_t MB = 1u << 20;
    char* ws = (char*)d_ws;
    unsigned short* qbf = (unsigned short*)(ws + 0 * MB);
    unsigned short* kbf = (unsigned short*)(ws + 8 * MB);
    unsigned short* vbf = (unsigned short*)(ws + 16 * MB);
    unsigned short* wqb = (unsigned short*)(ws + 24 * MB);
    unsigned short* wkb = (unsigned short*)(ws + 26 * MB);
    unsigned short* wvb = (unsigned short*)(ws + 28 * MB);
    unsigned short* wob = (unsigned short*)(ws + 30 * MB);
    unsigned short* QhB = (unsigned short*)(ws + 32 * MB);  // (B,H,L,D) bf16
    unsigned short* KhB = (unsigned short*)(ws + 40 * MB);
    unsigned short* VtB = (unsigned short*)(ws + 48 * MB);  // (B,H,D,L) bf16
    unsigned short* ctxB = (unsigned short*)(ws + 56 * MB); // (B,L,E) bf16
    float* mbias  = (float*)(ws + 64 * MB);                 // 16 KB
    // stats alias the qbf region (dead after the Q-projection GEMM)
    float* mstats = (float*)(ws + 0 * MB);                  // 256 KB
    float* lstats = (float*)(ws + 0 * MB + 256 * 1024);     // 256 KB

    bias_kernel<<<16, 256, 0, stream>>>(amask, kpm, mbias, Bsz * Lq);

    cvt_bf16<<<4096, 256, 0, stream>>>(query, qbf, 1048576);
    cvt_bf16<<<4096, 256, 0, stream>>>(key,   kbf, 1048576);
    cvt_bf16<<<4096, 256, 0, stream>>>(value, vbf, 1048576);
    cvt_bf16<<<1024, 256, 0, stream>>>(Wq, wqb, 262144);
    cvt_bf16<<<1024, 256, 0, stream>>>(Wk, wkb, 262144);
    cvt_bf16<<<1024, 256, 0, stream>>>(Wv, wvb, 262144);
    cvt_bf16<<<1024, 256, 0, stream>>>(Wo, wob, 262144);

    dim3 gg(8, 32), gb(256);
    gemm_bf16<0><<<gg, gb, 0, stream>>>(qbf, wqb, bq, QhB);
    gemm_bf16<0><<<gg, gb, 0, stream>>>(kbf, wkb, bk, KhB);
    gemm_bf16<2><<<gg, gb, 0, stream>>>(vbf, wvb, bv, VtB);

    attn_flash<<<dim3(16, 4, 16), 256, 0, stream>>>(QhB, KhB, VtB, mbias, ctxB, mstats, lstats);
    attn_out2<<<dim3(32, 8, 4), 256, 0, stream>>>(QhB, KhB, mbias, mstats, lstats, out2);

    gemm_bf16<1><<<gg, gb, 0, stream>>>(ctxB, wob, bo, out1);
}